// Round 1
// baseline (1251.036 us; speedup 1.0000x reference)
//
#include <hip/hip_runtime.h>

// BusStopPredictor: 2x SAGEConv(mean) + BN(eval) + ReLU, then Linear(64->1).
// N=50000 nodes, E=800000 edges, 32 -> 64 -> 64 -> 1.

constexpr int NN = 50000;
constexpr int NE = 800000;
constexpr float BN_EPS = 1e-5f;

// ---------------- degree histogram ----------------
__global__ __launch_bounds__(256) void k_deg(const int* __restrict__ ei,
                                             float* __restrict__ deg) {
    int e = blockIdx.x * 256 + threadIdx.x;
    if (e < NE) atomicAdd(&deg[ei[NE + e]], 1.0f);
}

// ---------------- edge scatter, 32 channels (layer 1) ----------------
// 8 lanes per edge, each lane handles 4 channels (float4).
__global__ __launch_bounds__(256) void k_scatter32(const int* __restrict__ ei,
                                                   const float* __restrict__ x,
                                                   float* __restrict__ agg) {
    int t = blockIdx.x * 256 + threadIdx.x;
    int e = t >> 3;
    if (e >= NE) return;
    int ch = (t & 7) << 2;
    int s = ei[e];
    int d = ei[NE + e];
    float4 v = *(const float4*)(x + (size_t)s * 32 + ch);
    float* p = agg + (size_t)d * 32 + ch;
    atomicAdd(p + 0, v.x);
    atomicAdd(p + 1, v.y);
    atomicAdd(p + 2, v.z);
    atomicAdd(p + 3, v.w);
}

// ---------------- edge scatter, 64 channels (layer 2) ----------------
// 16 lanes per edge, each lane handles 4 channels.
__global__ __launch_bounds__(256) void k_scatter64(const int* __restrict__ ei,
                                                   const float* __restrict__ h,
                                                   float* __restrict__ agg) {
    int t = blockIdx.x * 256 + threadIdx.x;
    int e = t >> 4;
    if (e >= NE) return;
    int ch = (t & 15) << 2;
    int s = ei[e];
    int d = ei[NE + e];
    float4 v = *(const float4*)(h + (size_t)s * 64 + ch);
    float* p = agg + (size_t)d * 64 + ch;
    atomicAdd(p + 0, v.x);
    atomicAdd(p + 1, v.y);
    atomicAdd(p + 2, v.z);
    atomicAdd(p + 3, v.w);
}

// ---------------- node update layer 1 ----------------
// h = relu(bn1(agg*deg_inv @ W1l + b1l + x @ W1r))
// One thread per node; weights read with wave-uniform indices -> scalar loads.
__global__ __launch_bounds__(256) void k_node1(
    const float* __restrict__ x, const float* __restrict__ agg,
    const float* __restrict__ deg,
    const float* __restrict__ W1l, const float* __restrict__ b1l,
    const float* __restrict__ W1r,
    const float* __restrict__ g1, const float* __restrict__ bb1,
    const float* __restrict__ m1, const float* __restrict__ v1,
    float* __restrict__ h) {
    int n = blockIdx.x * 256 + threadIdx.x;
    if (n >= NN) return;
    float di = 1.0f / fmaxf(deg[n], 1.0f);

    float acc[64];
#pragma unroll
    for (int o = 0; o < 64; o++) acc[o] = 0.0f;

    const float4* a4p = (const float4*)(agg + (size_t)n * 32);
    const float4* x4p = (const float4*)(x + (size_t)n * 32);
#pragma unroll
    for (int i0 = 0; i0 < 32; i0 += 4) {
        float4 a4 = a4p[i0 >> 2];
        float4 x4 = x4p[i0 >> 2];
        float av[4] = {a4.x * di, a4.y * di, a4.z * di, a4.w * di};
        float xv[4] = {x4.x, x4.y, x4.z, x4.w};
#pragma unroll
        for (int k = 0; k < 4; k++) {
            const float* wl = W1l + (size_t)(i0 + k) * 64;
            const float* wr = W1r + (size_t)(i0 + k) * 64;
#pragma unroll
            for (int o = 0; o < 64; o++) acc[o] += av[k] * wl[o] + xv[k] * wr[o];
        }
    }

    float* hp = h + (size_t)n * 64;
#pragma unroll
    for (int o4 = 0; o4 < 64; o4 += 4) {
        float4 r;
        float* rp = (float*)&r;
#pragma unroll
        for (int j = 0; j < 4; j++) {
            int o = o4 + j;
            float val = acc[o] + b1l[o];
            val = (val - m1[o]) * (g1[o] * rsqrtf(v1[o] + BN_EPS)) + bb1[o];
            rp[j] = fmaxf(val, 0.0f);
        }
        *(float4*)(hp + o4) = r;
    }
}

// ---------------- node update layer 2 + final linear ----------------
// out = relu(bn2(agg*deg_inv @ W2l + b2l + h @ W2r)) @ Wlin + blin
__global__ __launch_bounds__(256) void k_node2(
    const float* __restrict__ h, const float* __restrict__ agg,
    const float* __restrict__ deg,
    const float* __restrict__ W2l, const float* __restrict__ b2l,
    const float* __restrict__ W2r,
    const float* __restrict__ g2, const float* __restrict__ bb2,
    const float* __restrict__ m2, const float* __restrict__ v2,
    const float* __restrict__ Wlin, const float* __restrict__ blin,
    float* __restrict__ out) {
    int n = blockIdx.x * 256 + threadIdx.x;
    if (n >= NN) return;
    float di = 1.0f / fmaxf(deg[n], 1.0f);

    float acc[64];
#pragma unroll
    for (int o = 0; o < 64; o++) acc[o] = 0.0f;

    const float4* a4p = (const float4*)(agg + (size_t)n * 64);
    const float4* h4p = (const float4*)(h + (size_t)n * 64);
#pragma unroll 4
    for (int i0 = 0; i0 < 64; i0 += 4) {
        float4 a4 = a4p[i0 >> 2];
        float4 h4 = h4p[i0 >> 2];
        float av[4] = {a4.x * di, a4.y * di, a4.z * di, a4.w * di};
        float hv[4] = {h4.x, h4.y, h4.z, h4.w};
#pragma unroll
        for (int k = 0; k < 4; k++) {
            const float* wl = W2l + (size_t)(i0 + k) * 64;
            const float* wr = W2r + (size_t)(i0 + k) * 64;
#pragma unroll
            for (int o = 0; o < 64; o++) acc[o] += av[k] * wl[o] + hv[k] * wr[o];
        }
    }

    float sum = blin[0];
#pragma unroll
    for (int o = 0; o < 64; o++) {
        float val = acc[o] + b2l[o];
        val = (val - m2[o]) * (g2[o] * rsqrtf(v2[o] + BN_EPS)) + bb2[o];
        sum += fmaxf(val, 0.0f) * Wlin[o];
    }
    out[n] = sum;
}

extern "C" void kernel_launch(void* const* d_in, const int* in_sizes, int n_in,
                              void* d_out, int out_size, void* d_ws, size_t ws_size,
                              hipStream_t stream) {
    const float* x    = (const float*)d_in[0];
    const int*   ei   = (const int*)d_in[1];
    const float* W1l  = (const float*)d_in[2];
    const float* b1l  = (const float*)d_in[3];
    const float* W1r  = (const float*)d_in[4];
    const float* g1   = (const float*)d_in[5];
    const float* bb1  = (const float*)d_in[6];
    const float* m1   = (const float*)d_in[7];
    const float* v1   = (const float*)d_in[8];
    const float* W2l  = (const float*)d_in[9];
    const float* b2l  = (const float*)d_in[10];
    const float* W2r  = (const float*)d_in[11];
    const float* g2   = (const float*)d_in[12];
    const float* bb2  = (const float*)d_in[13];
    const float* m2   = (const float*)d_in[14];
    const float* v2   = (const float*)d_in[15];
    const float* Wlin = (const float*)d_in[16];
    const float* blin = (const float*)d_in[17];
    float* out = (float*)d_out;

    // ws layout (floats): deg [0, N) | agg [N, 65N) (reused for both layers) | h [65N, 129N)
    float* ws   = (float*)d_ws;
    float* deg  = ws;
    float* agg  = ws + NN;
    float* h    = ws + (size_t)65 * NN;

    // zero deg + agg (re-poisoned each launch)
    hipMemsetAsync(deg, 0, (size_t)(1 + 64) * NN * sizeof(float), stream);

    k_deg<<<(NE + 255) / 256, 256, 0, stream>>>(ei, deg);
    k_scatter32<<<(NE * 8 + 255) / 256, 256, 0, stream>>>(ei, x, agg);
    k_node1<<<(NN + 255) / 256, 256, 0, stream>>>(x, agg, deg, W1l, b1l, W1r,
                                                  g1, bb1, m1, v1, h);
    hipMemsetAsync(agg, 0, (size_t)64 * NN * sizeof(float), stream);
    k_scatter64<<<(NE * 16 + 255) / 256, 256, 0, stream>>>(ei, h, agg);
    k_node2<<<(NN + 255) / 256, 256, 0, stream>>>(h, agg, deg, W2l, b2l, W2r,
                                                  g2, bb2, m2, v2, Wlin, blin, out);
}

// Round 2
// 373.920 us; speedup vs baseline: 3.3457x; 3.3457x over previous
//
#include <hip/hip_runtime.h>

// BusStopPredictor: 2x SAGEConv(mean) + BN(eval) + ReLU, then Linear(64->1).
// N=50000 nodes, E=800000 edges, 32 -> 64 -> 64 -> 1.
//
// Strategy (round 1): replace edge-parallel float atomics (77M atomic RMWs,
// 658us for scatter64 alone) with a device-built dst-sorted CSR + per-node
// gather. CSR build costs only 1.6M int atomics (~20us); gathers are
// atomic-free L2/L3 reads.

constexpr int NN = 50000;
constexpr int NE = 800000;
constexpr int NB = (NN + 255) / 256;  // 196 blocks for node-sized scans
constexpr float BN_EPS = 1e-5f;

// ---------------- degree histogram (int) ----------------
__global__ __launch_bounds__(256) void k_deg(const int* __restrict__ ei,
                                             int* __restrict__ deg_i) {
    int e = blockIdx.x * 256 + threadIdx.x;
    if (e < NE) atomicAdd(&deg_i[ei[NE + e]], 1);
}

// ---------------- exclusive scan of deg -> base (3 kernels) ----------------
__global__ __launch_bounds__(256) void k_scan1(const int* __restrict__ deg_i,
                                               int* __restrict__ base,
                                               int* __restrict__ bsums) {
    __shared__ int s[256];
    int tid = threadIdx.x;
    int i = blockIdx.x * 256 + tid;
    int v = (i < NN) ? deg_i[i] : 0;
    s[tid] = v;
    __syncthreads();
#pragma unroll
    for (int off = 1; off < 256; off <<= 1) {
        int t = (tid >= off) ? s[tid - off] : 0;
        __syncthreads();
        s[tid] += t;
        __syncthreads();
    }
    if (i < NN) base[i] = s[tid] - v;  // exclusive within block
    if (tid == 255) bsums[blockIdx.x] = s[255];
}

__global__ __launch_bounds__(256) void k_scan2(int* __restrict__ bsums) {
    __shared__ int s[256];
    int tid = threadIdx.x;
    int v = (tid < NB) ? bsums[tid] : 0;
    s[tid] = v;
    __syncthreads();
#pragma unroll
    for (int off = 1; off < 256; off <<= 1) {
        int t = (tid >= off) ? s[tid - off] : 0;
        __syncthreads();
        s[tid] += t;
        __syncthreads();
    }
    if (tid < NB) bsums[tid] = s[tid] - v;  // exclusive block offsets
}

__global__ __launch_bounds__(256) void k_scan3(int* __restrict__ base,
                                               const int* __restrict__ bsums) {
    int i = blockIdx.x * 256 + threadIdx.x;
    if (i < NN) base[i] += bsums[blockIdx.x];
}

// ---------------- CSR fill: csr_src sorted by dst ----------------
// After this kernel, base[n] == row_end[n]; row_start[n] = base[n] - deg_i[n].
__global__ __launch_bounds__(256) void k_fill(const int* __restrict__ ei,
                                              int* __restrict__ base,
                                              int* __restrict__ csr_src) {
    int e = blockIdx.x * 256 + threadIdx.x;
    if (e >= NE) return;
    int s = ei[e];
    int d = ei[NE + e];
    int pos = atomicAdd(&base[d], 1);
    csr_src[pos] = s;
}

// ---------------- gather aggregation, 32 channels ----------------
// 8 lanes per node, each lane owns 4 channels.
__global__ __launch_bounds__(256) void k_gather32(const int* __restrict__ csr_src,
                                                  const int* __restrict__ base,
                                                  const int* __restrict__ deg_i,
                                                  const float* __restrict__ x,
                                                  float* __restrict__ agg) {
    int t = blockIdx.x * 256 + threadIdx.x;
    int n = t >> 3;
    if (n >= NN) return;
    int c4 = (t & 7) << 2;
    int end = base[n];
    int st = end - deg_i[n];
    float4 acc = make_float4(0.f, 0.f, 0.f, 0.f);
    for (int e = st; e < end; e++) {
        int s = csr_src[e];
        float4 v = *(const float4*)(x + (size_t)s * 32 + c4);
        acc.x += v.x; acc.y += v.y; acc.z += v.z; acc.w += v.w;
    }
    *(float4*)(agg + (size_t)n * 32 + c4) = acc;
}

// ---------------- gather aggregation, 64 channels ----------------
// 16 lanes per node, each lane owns 4 channels.
__global__ __launch_bounds__(256) void k_gather64(const int* __restrict__ csr_src,
                                                  const int* __restrict__ base,
                                                  const int* __restrict__ deg_i,
                                                  const float* __restrict__ h,
                                                  float* __restrict__ agg) {
    int t = blockIdx.x * 256 + threadIdx.x;
    int n = t >> 4;
    if (n >= NN) return;
    int c4 = (t & 15) << 2;
    int end = base[n];
    int st = end - deg_i[n];
    float4 acc = make_float4(0.f, 0.f, 0.f, 0.f);
    for (int e = st; e < end; e++) {
        int s = csr_src[e];
        float4 v = *(const float4*)(h + (size_t)s * 64 + c4);
        acc.x += v.x; acc.y += v.y; acc.z += v.z; acc.w += v.w;
    }
    *(float4*)(agg + (size_t)n * 64 + c4) = acc;
}

// ---------------- node update layer 1 ----------------
// h = relu(bn1(agg*deg_inv @ W1l + b1l + x @ W1r))
__global__ __launch_bounds__(256) void k_node1(
    const float* __restrict__ x, const float* __restrict__ agg,
    const int* __restrict__ deg_i,
    const float* __restrict__ W1l, const float* __restrict__ b1l,
    const float* __restrict__ W1r,
    const float* __restrict__ g1, const float* __restrict__ bb1,
    const float* __restrict__ m1, const float* __restrict__ v1,
    float* __restrict__ h) {
    int n = blockIdx.x * 256 + threadIdx.x;
    if (n >= NN) return;
    float di = 1.0f / fmaxf((float)deg_i[n], 1.0f);

    float acc[64];
#pragma unroll
    for (int o = 0; o < 64; o++) acc[o] = 0.0f;

    const float4* a4p = (const float4*)(agg + (size_t)n * 32);
    const float4* x4p = (const float4*)(x + (size_t)n * 32);
#pragma unroll
    for (int i0 = 0; i0 < 32; i0 += 4) {
        float4 a4 = a4p[i0 >> 2];
        float4 x4 = x4p[i0 >> 2];
        float av[4] = {a4.x * di, a4.y * di, a4.z * di, a4.w * di};
        float xv[4] = {x4.x, x4.y, x4.z, x4.w};
#pragma unroll
        for (int k = 0; k < 4; k++) {
            const float* wl = W1l + (size_t)(i0 + k) * 64;
            const float* wr = W1r + (size_t)(i0 + k) * 64;
#pragma unroll
            for (int o = 0; o < 64; o++) acc[o] += av[k] * wl[o] + xv[k] * wr[o];
        }
    }

    float* hp = h + (size_t)n * 64;
#pragma unroll
    for (int o4 = 0; o4 < 64; o4 += 4) {
        float4 r;
        float* rp = (float*)&r;
#pragma unroll
        for (int j = 0; j < 4; j++) {
            int o = o4 + j;
            float val = acc[o] + b1l[o];
            val = (val - m1[o]) * (g1[o] * rsqrtf(v1[o] + BN_EPS)) + bb1[o];
            rp[j] = fmaxf(val, 0.0f);
        }
        *(float4*)(hp + o4) = r;
    }
}

// ---------------- node update layer 2 + final linear ----------------
// out = relu(bn2(agg*deg_inv @ W2l + b2l + h @ W2r)) @ Wlin + blin
__global__ __launch_bounds__(256) void k_node2(
    const float* __restrict__ h, const float* __restrict__ agg,
    const int* __restrict__ deg_i,
    const float* __restrict__ W2l, const float* __restrict__ b2l,
    const float* __restrict__ W2r,
    const float* __restrict__ g2, const float* __restrict__ bb2,
    const float* __restrict__ m2, const float* __restrict__ v2,
    const float* __restrict__ Wlin, const float* __restrict__ blin,
    float* __restrict__ out) {
    int n = blockIdx.x * 256 + threadIdx.x;
    if (n >= NN) return;
    float di = 1.0f / fmaxf((float)deg_i[n], 1.0f);

    float acc[64];
#pragma unroll
    for (int o = 0; o < 64; o++) acc[o] = 0.0f;

    const float4* a4p = (const float4*)(agg + (size_t)n * 64);
    const float4* h4p = (const float4*)(h + (size_t)n * 64);
#pragma unroll 4
    for (int i0 = 0; i0 < 64; i0 += 4) {
        float4 a4 = a4p[i0 >> 2];
        float4 h4 = h4p[i0 >> 2];
        float av[4] = {a4.x * di, a4.y * di, a4.z * di, a4.w * di};
        float hv[4] = {h4.x, h4.y, h4.z, h4.w};
#pragma unroll
        for (int k = 0; k < 4; k++) {
            const float* wl = W2l + (size_t)(i0 + k) * 64;
            const float* wr = W2r + (size_t)(i0 + k) * 64;
#pragma unroll
            for (int o = 0; o < 64; o++) acc[o] += av[k] * wl[o] + hv[k] * wr[o];
        }
    }

    float sum = blin[0];
#pragma unroll
    for (int o = 0; o < 64; o++) {
        float val = acc[o] + b2l[o];
        val = (val - m2[o]) * (g2[o] * rsqrtf(v2[o] + BN_EPS)) + bb2[o];
        sum += fmaxf(val, 0.0f) * Wlin[o];
    }
    out[n] = sum;
}

extern "C" void kernel_launch(void* const* d_in, const int* in_sizes, int n_in,
                              void* d_out, int out_size, void* d_ws, size_t ws_size,
                              hipStream_t stream) {
    const float* x    = (const float*)d_in[0];
    const int*   ei   = (const int*)d_in[1];
    const float* W1l  = (const float*)d_in[2];
    const float* b1l  = (const float*)d_in[3];
    const float* W1r  = (const float*)d_in[4];
    const float* g1   = (const float*)d_in[5];
    const float* bb1  = (const float*)d_in[6];
    const float* m1   = (const float*)d_in[7];
    const float* v1   = (const float*)d_in[8];
    const float* W2l  = (const float*)d_in[9];
    const float* b2l  = (const float*)d_in[10];
    const float* W2r  = (const float*)d_in[11];
    const float* g2   = (const float*)d_in[12];
    const float* bb2  = (const float*)d_in[13];
    const float* m2   = (const float*)d_in[14];
    const float* v2   = (const float*)d_in[15];
    const float* Wlin = (const float*)d_in[16];
    const float* blin = (const float*)d_in[17];
    float* out = (float*)d_out;

    // ws layout:
    //   deg_i  int[N]      degree per dst node
    //   base   int[N]      exclusive scan of deg (becomes row_end after fill)
    //   bsums  int[256]    scan block sums
    //   csr    int[E]      src indices sorted by dst
    //   agg    float[64N]  aggregation buffer (reused both layers)
    //   h      float[64N]  layer-1 output
    int* deg_i = (int*)d_ws;
    int* base  = deg_i + NN;
    int* bsums = base + NN;
    int* csr   = bsums + 256;
    float* agg = (float*)(csr + NE);
    float* h   = agg + (size_t)64 * NN;

    // only deg needs zeroing; everything else is fully overwritten
    hipMemsetAsync(deg_i, 0, (size_t)NN * sizeof(int), stream);

    k_deg<<<(NE + 255) / 256, 256, 0, stream>>>(ei, deg_i);
    k_scan1<<<NB, 256, 0, stream>>>(deg_i, base, bsums);
    k_scan2<<<1, 256, 0, stream>>>(bsums);
    k_scan3<<<NB, 256, 0, stream>>>(base, bsums);
    k_fill<<<(NE + 255) / 256, 256, 0, stream>>>(ei, base, csr);

    k_gather32<<<(NN * 8 + 255) / 256, 256, 0, stream>>>(csr, base, deg_i, x, agg);
    k_node1<<<NB, 256, 0, stream>>>(x, agg, deg_i, W1l, b1l, W1r,
                                    g1, bb1, m1, v1, h);
    k_gather64<<<(NN * 16 + 255) / 256, 256, 0, stream>>>(csr, base, deg_i, h, agg);
    k_node2<<<NB, 256, 0, stream>>>(h, agg, deg_i, W2l, b2l, W2r,
                                    g2, bb2, m2, v2, Wlin, blin, out);
}

// Round 4
// 336.681 us; speedup vs baseline: 3.7158x; 1.1106x over previous
//
#include <hip/hip_runtime.h>

// BusStopPredictor: 2x SAGEConv(mean) + BN(eval) + ReLU, then Linear(64->1).
// N=50000 nodes, E=800000 edges, 32 -> 64 -> 64 -> 1.
//
// Round 1: dst-sorted CSR + per-node gather (no float atomics): 1251 -> 374us.
// Round 2: node GEMMs re-mapped 1-thread-per-node -> 16-lanes-per-node
//          (4 out-channels per lane). Old mapping was grid-bound: 196 blocks,
//          8.5% occupancy, 14% VALUBusy, 87us for node2 alone.
// Round 3: resubmit unchanged (round-2 bench hit GPUAcquisitionTimeout).

constexpr int NN = 50000;
constexpr int NE = 800000;
constexpr int NB = (NN + 255) / 256;  // 196 blocks for node-sized scans
constexpr float BN_EPS = 1e-5f;

// ---------------- degree histogram (int) ----------------
__global__ __launch_bounds__(256) void k_deg(const int* __restrict__ ei,
                                             int* __restrict__ deg_i) {
    int e = blockIdx.x * 256 + threadIdx.x;
    if (e < NE) atomicAdd(&deg_i[ei[NE + e]], 1);
}

// ---------------- exclusive scan of deg -> base (3 kernels) ----------------
__global__ __launch_bounds__(256) void k_scan1(const int* __restrict__ deg_i,
                                               int* __restrict__ base,
                                               int* __restrict__ bsums) {
    __shared__ int s[256];
    int tid = threadIdx.x;
    int i = blockIdx.x * 256 + tid;
    int v = (i < NN) ? deg_i[i] : 0;
    s[tid] = v;
    __syncthreads();
#pragma unroll
    for (int off = 1; off < 256; off <<= 1) {
        int t = (tid >= off) ? s[tid - off] : 0;
        __syncthreads();
        s[tid] += t;
        __syncthreads();
    }
    if (i < NN) base[i] = s[tid] - v;  // exclusive within block
    if (tid == 255) bsums[blockIdx.x] = s[255];
}

__global__ __launch_bounds__(256) void k_scan2(int* __restrict__ bsums) {
    __shared__ int s[256];
    int tid = threadIdx.x;
    int v = (tid < NB) ? bsums[tid] : 0;
    s[tid] = v;
    __syncthreads();
#pragma unroll
    for (int off = 1; off < 256; off <<= 1) {
        int t = (tid >= off) ? s[tid - off] : 0;
        __syncthreads();
        s[tid] += t;
        __syncthreads();
    }
    if (tid < NB) bsums[tid] = s[tid] - v;  // exclusive block offsets
}

__global__ __launch_bounds__(256) void k_scan3(int* __restrict__ base,
                                               const int* __restrict__ bsums) {
    int i = blockIdx.x * 256 + threadIdx.x;
    if (i < NN) base[i] += bsums[blockIdx.x];
}

// ---------------- CSR fill: csr_src sorted by dst ----------------
// After this kernel, base[n] == row_end[n]; row_start[n] = base[n] - deg_i[n].
__global__ __launch_bounds__(256) void k_fill(const int* __restrict__ ei,
                                              int* __restrict__ base,
                                              int* __restrict__ csr_src) {
    int e = blockIdx.x * 256 + threadIdx.x;
    if (e >= NE) return;
    int s = ei[e];
    int d = ei[NE + e];
    int pos = atomicAdd(&base[d], 1);
    csr_src[pos] = s;
}

// ---------------- gather aggregation, 32 channels ----------------
// 8 lanes per node, each lane owns 4 channels.
__global__ __launch_bounds__(256) void k_gather32(const int* __restrict__ csr_src,
                                                  const int* __restrict__ base,
                                                  const int* __restrict__ deg_i,
                                                  const float* __restrict__ x,
                                                  float* __restrict__ agg) {
    int t = blockIdx.x * 256 + threadIdx.x;
    int n = t >> 3;
    if (n >= NN) return;
    int c4 = (t & 7) << 2;
    int end = base[n];
    int st = end - deg_i[n];
    float4 acc = make_float4(0.f, 0.f, 0.f, 0.f);
    for (int e = st; e < end; e++) {
        int s = csr_src[e];
        float4 v = *(const float4*)(x + (size_t)s * 32 + c4);
        acc.x += v.x; acc.y += v.y; acc.z += v.z; acc.w += v.w;
    }
    *(float4*)(agg + (size_t)n * 32 + c4) = acc;
}

// ---------------- gather aggregation, 64 channels ----------------
// 16 lanes per node, each lane owns 4 channels.
__global__ __launch_bounds__(256) void k_gather64(const int* __restrict__ csr_src,
                                                  const int* __restrict__ base,
                                                  const int* __restrict__ deg_i,
                                                  const float* __restrict__ h,
                                                  float* __restrict__ agg) {
    int t = blockIdx.x * 256 + threadIdx.x;
    int n = t >> 4;
    if (n >= NN) return;
    int c4 = (t & 15) << 2;
    int end = base[n];
    int st = end - deg_i[n];
    float4 acc = make_float4(0.f, 0.f, 0.f, 0.f);
    for (int e = st; e < end; e++) {
        int s = csr_src[e];
        float4 v = *(const float4*)(h + (size_t)s * 64 + c4);
        acc.x += v.x; acc.y += v.y; acc.z += v.z; acc.w += v.w;
    }
    *(float4*)(agg + (size_t)n * 64 + c4) = acc;
}

// ---------------- node update layer 1 ----------------
// h = relu(bn1(agg*deg_inv @ W1l + b1l + x @ W1r))
// 16 lanes per node, 4 output channels per lane. Weight reads: 16 lanes x
// float4 = one coalesced 256B row per (matrix, k). Input reads: float4
// broadcast within the 16-lane group (L1-served).
__global__ __launch_bounds__(256) void k_node1(
    const float* __restrict__ x, const float* __restrict__ agg,
    const int* __restrict__ deg_i,
    const float* __restrict__ W1l, const float* __restrict__ b1l,
    const float* __restrict__ W1r,
    const float* __restrict__ g1, const float* __restrict__ bb1,
    const float* __restrict__ m1, const float* __restrict__ v1,
    float* __restrict__ h) {
    int t = blockIdx.x * 256 + threadIdx.x;
    int n = t >> 4;
    if (n >= NN) return;
    int o4 = (t & 15) << 2;
    float di = 1.0f / fmaxf((float)deg_i[n], 1.0f);

    const float* ar = agg + (size_t)n * 32;
    const float* xr = x + (size_t)n * 32;
    float4 acc = make_float4(0.f, 0.f, 0.f, 0.f);
#pragma unroll
    for (int i4 = 0; i4 < 32; i4 += 4) {
        float4 a4 = *(const float4*)(ar + i4);
        float4 x4 = *(const float4*)(xr + i4);
        float av[4] = {a4.x * di, a4.y * di, a4.z * di, a4.w * di};
        float xv[4] = {x4.x, x4.y, x4.z, x4.w};
#pragma unroll
        for (int k = 0; k < 4; k++) {
            float4 wl = *(const float4*)(W1l + (size_t)(i4 + k) * 64 + o4);
            float4 wr = *(const float4*)(W1r + (size_t)(i4 + k) * 64 + o4);
            acc.x += av[k] * wl.x + xv[k] * wr.x;
            acc.y += av[k] * wl.y + xv[k] * wr.y;
            acc.z += av[k] * wl.z + xv[k] * wr.z;
            acc.w += av[k] * wl.w + xv[k] * wr.w;
        }
    }

    float4 bl = *(const float4*)(b1l + o4);
    float4 gg = *(const float4*)(g1 + o4);
    float4 bb = *(const float4*)(bb1 + o4);
    float4 mm = *(const float4*)(m1 + o4);
    float4 vv = *(const float4*)(v1 + o4);
    float4 r;
    r.x = fmaxf((acc.x + bl.x - mm.x) * (gg.x * rsqrtf(vv.x + BN_EPS)) + bb.x, 0.0f);
    r.y = fmaxf((acc.y + bl.y - mm.y) * (gg.y * rsqrtf(vv.y + BN_EPS)) + bb.y, 0.0f);
    r.z = fmaxf((acc.z + bl.z - mm.z) * (gg.z * rsqrtf(vv.z + BN_EPS)) + bb.z, 0.0f);
    r.w = fmaxf((acc.w + bl.w - mm.w) * (gg.w * rsqrtf(vv.w + BN_EPS)) + bb.w, 0.0f);
    *(float4*)(h + (size_t)n * 64 + o4) = r;
}

// ---------------- node update layer 2 + final linear ----------------
// out = relu(bn2(agg*deg_inv @ W2l + b2l + h @ W2r)) @ Wlin + blin
// Same 16-lanes-per-node mapping; final dot reduced across the 16-lane group.
__global__ __launch_bounds__(256) void k_node2(
    const float* __restrict__ h, const float* __restrict__ agg,
    const int* __restrict__ deg_i,
    const float* __restrict__ W2l, const float* __restrict__ b2l,
    const float* __restrict__ W2r,
    const float* __restrict__ g2, const float* __restrict__ bb2,
    const float* __restrict__ m2, const float* __restrict__ v2,
    const float* __restrict__ Wlin, const float* __restrict__ blin,
    float* __restrict__ out) {
    int t = blockIdx.x * 256 + threadIdx.x;
    int n = t >> 4;
    if (n >= NN) return;
    int lg = t & 15;
    int o4 = lg << 2;
    float di = 1.0f / fmaxf((float)deg_i[n], 1.0f);

    const float* ar = agg + (size_t)n * 64;
    const float* hr = h + (size_t)n * 64;
    float4 acc = make_float4(0.f, 0.f, 0.f, 0.f);
#pragma unroll
    for (int i4 = 0; i4 < 64; i4 += 4) {
        float4 a4 = *(const float4*)(ar + i4);
        float4 h4 = *(const float4*)(hr + i4);
        float av[4] = {a4.x * di, a4.y * di, a4.z * di, a4.w * di};
        float hv[4] = {h4.x, h4.y, h4.z, h4.w};
#pragma unroll
        for (int k = 0; k < 4; k++) {
            float4 wl = *(const float4*)(W2l + (size_t)(i4 + k) * 64 + o4);
            float4 wr = *(const float4*)(W2r + (size_t)(i4 + k) * 64 + o4);
            acc.x += av[k] * wl.x + hv[k] * wr.x;
            acc.y += av[k] * wl.y + hv[k] * wr.y;
            acc.z += av[k] * wl.z + hv[k] * wr.z;
            acc.w += av[k] * wl.w + hv[k] * wr.w;
        }
    }

    float4 bl = *(const float4*)(b2l + o4);
    float4 gg = *(const float4*)(g2 + o4);
    float4 bb = *(const float4*)(bb2 + o4);
    float4 mm = *(const float4*)(m2 + o4);
    float4 vv = *(const float4*)(v2 + o4);
    float4 wo = *(const float4*)(Wlin + o4);
    float part;
    {
        float vx = fmaxf((acc.x + bl.x - mm.x) * (gg.x * rsqrtf(vv.x + BN_EPS)) + bb.x, 0.0f);
        float vy = fmaxf((acc.y + bl.y - mm.y) * (gg.y * rsqrtf(vv.y + BN_EPS)) + bb.y, 0.0f);
        float vz = fmaxf((acc.z + bl.z - mm.z) * (gg.z * rsqrtf(vv.z + BN_EPS)) + bb.z, 0.0f);
        float vw = fmaxf((acc.w + bl.w - mm.w) * (gg.w * rsqrtf(vv.w + BN_EPS)) + bb.w, 0.0f);
        part = vx * wo.x + vy * wo.y + vz * wo.z + vw * wo.w;
    }
#pragma unroll
    for (int m = 1; m < 16; m <<= 1) part += __shfl_xor(part, m, 64);
    if (lg == 0) out[n] = part + blin[0];
}

extern "C" void kernel_launch(void* const* d_in, const int* in_sizes, int n_in,
                              void* d_out, int out_size, void* d_ws, size_t ws_size,
                              hipStream_t stream) {
    const float* x    = (const float*)d_in[0];
    const int*   ei   = (const int*)d_in[1];
    const float* W1l  = (const float*)d_in[2];
    const float* b1l  = (const float*)d_in[3];
    const float* W1r  = (const float*)d_in[4];
    const float* g1   = (const float*)d_in[5];
    const float* bb1  = (const float*)d_in[6];
    const float* m1   = (const float*)d_in[7];
    const float* v1   = (const float*)d_in[8];
    const float* W2l  = (const float*)d_in[9];
    const float* b2l  = (const float*)d_in[10];
    const float* W2r  = (const float*)d_in[11];
    const float* g2   = (const float*)d_in[12];
    const float* bb2  = (const float*)d_in[13];
    const float* m2   = (const float*)d_in[14];
    const float* v2   = (const float*)d_in[15];
    const float* Wlin = (const float*)d_in[16];
    const float* blin = (const float*)d_in[17];
    float* out = (float*)d_out;

    // ws layout:
    //   deg_i  int[N]      degree per dst node
    //   base   int[N]      exclusive scan of deg (becomes row_end after fill)
    //   bsums  int[256]    scan block sums
    //   csr    int[E]      src indices sorted by dst
    //   agg    float[64N]  aggregation buffer (reused both layers)
    //   h      float[64N]  layer-1 output
    int* deg_i = (int*)d_ws;
    int* base  = deg_i + NN;
    int* bsums = base + NN;
    int* csr   = bsums + 256;
    float* agg = (float*)(csr + NE);
    float* h   = agg + (size_t)64 * NN;

    // only deg needs zeroing; everything else is fully overwritten
    hipMemsetAsync(deg_i, 0, (size_t)NN * sizeof(int), stream);

    k_deg<<<(NE + 255) / 256, 256, 0, stream>>>(ei, deg_i);
    k_scan1<<<NB, 256, 0, stream>>>(deg_i, base, bsums);
    k_scan2<<<1, 256, 0, stream>>>(bsums);
    k_scan3<<<NB, 256, 0, stream>>>(base, bsums);
    k_fill<<<(NE + 255) / 256, 256, 0, stream>>>(ei, base, csr);

    k_gather32<<<(NN * 8 + 255) / 256, 256, 0, stream>>>(csr, base, deg_i, x, agg);
    k_node1<<<(NN * 16 + 255) / 256, 256, 0, stream>>>(x, agg, deg_i, W1l, b1l, W1r,
                                                       g1, bb1, m1, v1, h);
    k_gather64<<<(NN * 16 + 255) / 256, 256, 0, stream>>>(csr, base, deg_i, h, agg);
    k_node2<<<(NN * 16 + 255) / 256, 256, 0, stream>>>(h, agg, deg_i, W2l, b2l, W2r,
                                                       g2, bb2, m2, v2, Wlin, blin, out);
}